// Round 6
// baseline (516.768 us; speedup 1.0000x reference)
//
#include <hip/hip_runtime.h>
#include <math.h>

#define B_ 16
#define HEADS_ 8
#define G_ 64          // == L
#define DH_ 64
#define N_ 3131
#define DM_ 512
#define NH_ 8
#define DINPROJ_ 1042
#define CONVDIM_ 514
#define DIM_ 512

#define OUT0_OFS 0
#define OUT1_OFS (B_*N_*DIM_)
#define OUT2_OFS (B_*N_*DIM_ + B_*HEADS_*G_*DH_)

typedef __attribute__((ext_vector_type(8))) short short8;
typedef __attribute__((ext_vector_type(4))) float f32x4;

__device__ __forceinline__ float siluf(float v){ return v / (1.f + expf(-v)); }
__device__ __forceinline__ float softplusf(float v){ return (v > 20.f) ? v : log1pf(expf(v)); }
__device__ __forceinline__ unsigned short f2bf(float f){
    unsigned int u = __float_as_uint(f);
    unsigned int r = (u + 0x7fffu + ((u >> 16) & 1u)) >> 16;
    return (unsigned short)r;
}

// ---------------------------------------------------------------------------
// k1: zx[bl][j] = sum_d u[bl][d] * w_in[j][d]
__global__ void k1_inproj(const float* __restrict__ st,
                          const float* __restrict__ w_in,
                          float* __restrict__ zx) {
    __shared__ float Ast[64][68];   // [c][l]
    __shared__ float Bs[64][68];    // [c][jl]
    int j0 = blockIdx.x * 64;
    int b  = blockIdx.y;
    int tid = threadIdx.x, tx = tid & 15, ty = tid >> 4;
    float acc[4][4];
#pragma unroll
    for (int i = 0; i < 4; i++)
#pragma unroll
        for (int j = 0; j < 4; j++) acc[i][j] = 0.f;

    for (int h = 0; h < 8; h++) {
        const float* Ab = st + ((size_t)(b*8 + h) * 64) * 64;
        for (int i = tid; i < 1024; i += 256) {
            int l = i >> 4, cq = i & 15;
            float4 v = *(const float4*)(Ab + l*64 + cq*4);
            Ast[cq*4+0][l] = v.x; Ast[cq*4+1][l] = v.y;
            Ast[cq*4+2][l] = v.z; Ast[cq*4+3][l] = v.w;
        }
        for (int i = tid; i < 1024; i += 256) {
            int jl = i >> 4, cq = i & 15;
            int j = j0 + jl;
            float4 v = make_float4(0.f,0.f,0.f,0.f);
            if (j < DINPROJ_) v = *(const float4*)(w_in + (size_t)j*DM_ + h*64 + cq*4);
            Bs[cq*4+0][jl] = v.x; Bs[cq*4+1][jl] = v.y;
            Bs[cq*4+2][jl] = v.z; Bs[cq*4+3][jl] = v.w;
        }
        __syncthreads();
#pragma unroll 8
        for (int k = 0; k < 64; k++) {
            float4 av = *(const float4*)&Ast[k][ty*4];
            float4 bv = *(const float4*)&Bs[k][tx*4];
            float aa[4] = {av.x, av.y, av.z, av.w};
            float bb[4] = {bv.x, bv.y, bv.z, bv.w};
#pragma unroll
            for (int i = 0; i < 4; i++)
#pragma unroll
                for (int j = 0; j < 4; j++) acc[i][j] += aa[i]*bb[j];
        }
        __syncthreads();
    }
#pragma unroll
    for (int i = 0; i < 4; i++) {
        int bl = b*64 + ty*4 + i;
#pragma unroll
        for (int j = 0; j < 4; j++) {
            int jj = j0 + tx*4 + j;
            if (jj < DINPROJ_) zx[(size_t)bl*DINPROJ_ + jj] = acc[i][j];
        }
    }
}

// ---------------------------------------------------------------------------
// k2: conv3+silu -> x,(B,C); scan tables a=exp(dt*A), bb=dt*Bv; dcoef
// (zs removed: k4a computes silu(z) inline from zx)
__global__ void k2_conv(const float* __restrict__ zx,
                        const float* __restrict__ conv_w,
                        const float* __restrict__ conv_b,
                        const float* __restrict__ dt_bias,
                        const float* __restrict__ A_log,
                        const float* __restrict__ fc_D_w,
                        const float* __restrict__ Dvec,
                        float* __restrict__ x,
                        float* __restrict__ Cv, float* __restrict__ tblf,
                        float* __restrict__ dco) {
    int bl = blockIdx.x; int b = bl >> 6, l = bl & 63;
    __shared__ float sx[DM_];
    __shared__ float sBv;
    const float* zrow = zx + (size_t)bl * DINPROJ_;

    for (int ch = threadIdx.x; ch < CONVDIM_; ch += 256) {
        float v = conv_b[ch];
#pragma unroll
        for (int k = 0; k < 3; k++) {
            int t = l - 2 + k;
            if (t >= 0) v += conv_w[ch*3 + k] * zx[(size_t)(b*G_ + t) * DINPROJ_ + DM_ + ch];
        }
        float sv = siluf(v);
        if (ch < DM_)      { x[(size_t)bl*DM_ + ch] = sv; sx[ch] = sv; }
        else if (ch == DM_){ sBv = sv; }
        else               { Cv[bl] = sv; }
    }
    __syncthreads();
    if (threadIdx.x < 16) {
        int i = threadIdx.x; int h = i & 7;
        float dt = softplusf(zrow[DM_ + CONVDIM_ + i] + dt_bias[h]);
        float Ah = -expf(A_log[h]);
        float a  = expf(dt * Ah);
        float bb = dt * sBv;
        float* t4 = tblf + ((size_t)bl*NH_ + h)*4;
        if (i < 8) { t4[0] = a; t4[1] = bb; }
        else       { t4[2] = a; t4[3] = bb; }
    }
    // dco: all 256 threads; 32 lanes per head, float4 loads, shuffle reduce
    {
        int h = threadIdx.x >> 5, l32 = threadIdx.x & 31;
        const float* fr = fc_D_w + (size_t)h * DM_;
        float s = 0.f;
#pragma unroll
        for (int q = 0; q < 4; q++) {
            int d = q*128 + l32*4;
            float4 w4 = *(const float4*)(fr + d);
            float4 x4 = *(const float4*)(&sx[d]);
            s += w4.x*x4.x + w4.y*x4.y + w4.z*x4.z + w4.w*x4.w;
        }
#pragma unroll
        for (int o = 16; o > 0; o >>= 1) s += __shfl_down(s, o, 32);
        if (l32 == 0) dco[bl*NH_ + h] = s + Dvec[h];
    }
}

// ---------------------------------------------------------------------------
// k3: directional scan. dir=0: yfw = dterm + y_fw ; dir=1: ybw = y_bw
// grid (B_*HEADS_, 2), 64 threads
__global__ void k3_scan(const float* __restrict__ x, const float* __restrict__ Cv,
                        const float* __restrict__ tblf, const float* __restrict__ dco,
                        float* __restrict__ yfw, float* __restrict__ ybw) {
    int bh = blockIdx.x; int b = bh >> 3, h = bh & 7;
    int dir = blockIdx.y;
    int c = threadIdx.x;
    __shared__ float sA[64], sB[64], sC[64], sD[64];
    {
        int bl = b*64 + c;
        const float* t4 = tblf + ((size_t)bl*NH_ + h)*4;
        sA[c] = dir ? t4[2] : t4[0];
        sB[c] = dir ? t4[3] : t4[1];
        sC[c] = Cv[bl];
        sD[c] = dco[bl*NH_ + h];
    }
    __syncthreads();
    const float* xr = x + (size_t)(b*64)*DM_ + h*64 + c;
    if (dir == 0) {
        float* yw = yfw + (size_t)(b*64)*DM_ + h*64 + c;
        float state = 0.f;
        float xv = xr[0];
#pragma unroll 4
        for (int t = 0; t < 64; t++) {
            float xn = (t < 63) ? xr[(t+1)*DM_] : 0.f;
            float val = xv * sD[t];
            if (t > 0) val += state * sC[t-1];
            yw[t*DM_] = val;
            state = sA[t]*state + sB[t]*xv;
            xv = xn;
        }
    } else {
        float* yw = ybw + (size_t)(b*64)*DM_ + h*64 + c;
        float state = 0.f;
        float xv = xr[63*DM_];
#pragma unroll 4
        for (int s = 63; s >= 0; s--) {
            float xn = (s > 0) ? xr[(s-1)*DM_] : 0.f;
            float val = (s < 63) ? state * sC[s+1] : 0.f;
            yw[s*DM_] = val;
            state = sA[s]*state + sB[s]*xv;
            xv = xn;
        }
    }
}

// ---------------------------------------------------------------------------
// k4a: y = (yfw+ybw)*silu(z from zx) ; RMSNorm -> yn
__global__ void k4a_rms(const float* __restrict__ yfw, const float* __restrict__ ybw,
                        const float* __restrict__ zx, const float* __restrict__ norm_w,
                        float* __restrict__ yn) {
    int bl = blockIdx.x;
    __shared__ float red[4];
    const float* zrow = zx + (size_t)bl * DINPROJ_;
    float vv[2]; float ss = 0.f;
#pragma unroll
    for (int r = 0; r < 2; r++) {
        int d = threadIdx.x + r*256;
        size_t i = (size_t)bl*DM_ + d;
        float v = (yfw[i] + ybw[i]) * siluf(zrow[d]);
        vv[r] = v; ss += v*v;
    }
#pragma unroll
    for (int o = 32; o > 0; o >>= 1) ss += __shfl_down(ss, o, 64);
    if ((threadIdx.x & 63) == 0) red[threadIdx.x >> 6] = ss;
    __syncthreads();
    float scale = rsqrtf((red[0]+red[1]+red[2]+red[3]) / (float)DM_ + 1e-5f);
#pragma unroll
    for (int r = 0; r < 2; r++) {
        int d = threadIdx.x + r*256;
        yn[(size_t)bl*DM_ + d] = vv[r] * scale * norm_w[d];
    }
}

// ---------------------------------------------------------------------------
// k4b: om[bl][j] = sum_d yn[bl][d]*w_out[j][d]; also out2
__global__ void k4b_wout(const float* __restrict__ yn,
                         const float* __restrict__ w_out,
                         float* __restrict__ om, float* __restrict__ out2) {
    __shared__ float Ast[64][68];
    __shared__ float Bs[64][68];
    int j0 = blockIdx.x * 64;
    int b  = blockIdx.y;
    int tid = threadIdx.x, tx = tid & 15, ty = tid >> 4;
    float acc[4][4];
#pragma unroll
    for (int i = 0; i < 4; i++)
#pragma unroll
        for (int j = 0; j < 4; j++) acc[i][j] = 0.f;

    for (int kt = 0; kt < 8; kt++) {
        const float* Ab = yn + (size_t)(b*64)*DM_ + kt*64;
        for (int i = tid; i < 1024; i += 256) {
            int l = i >> 4, cq = i & 15;
            float4 v = *(const float4*)(Ab + (size_t)l*DM_ + cq*4);
            Ast[cq*4+0][l] = v.x; Ast[cq*4+1][l] = v.y;
            Ast[cq*4+2][l] = v.z; Ast[cq*4+3][l] = v.w;
        }
        for (int i = tid; i < 1024; i += 256) {
            int jl = i >> 4, cq = i & 15;
            float4 v = *(const float4*)(w_out + (size_t)(j0 + jl)*DM_ + kt*64 + cq*4);
            Bs[cq*4+0][jl] = v.x; Bs[cq*4+1][jl] = v.y;
            Bs[cq*4+2][jl] = v.z; Bs[cq*4+3][jl] = v.w;
        }
        __syncthreads();
#pragma unroll 8
        for (int k = 0; k < 64; k++) {
            float4 av = *(const float4*)&Ast[k][ty*4];
            float4 bv = *(const float4*)&Bs[k][tx*4];
            float aa[4] = {av.x, av.y, av.z, av.w};
            float bb[4] = {bv.x, bv.y, bv.z, bv.w};
#pragma unroll
            for (int i = 0; i < 4; i++)
#pragma unroll
                for (int j = 0; j < 4; j++) acc[i][j] += aa[i]*bb[j];
        }
        __syncthreads();
    }
#pragma unroll
    for (int i = 0; i < 4; i++) {
        int l = ty*4 + i, bl = b*64 + l;
        float4 v = make_float4(acc[i][0], acc[i][1], acc[i][2], acc[i][3]);
        *(float4*)(om + (size_t)bl*DM_ + j0 + tx*4) = v;
        *(float4*)(out2 + (((size_t)(b*8 + blockIdx.x)*64 + l) << 6) + tx*4) = v;
    }
}

// ---------------------------------------------------------------------------
// k5: Pbf[b][d][h*64+g] = bf16( sum_c om[b,g,h*64+c] * to_out_w[d,h*64+c] )
// Block-diagonal per head: tiled fp32 outer-product GEMM, no spill.
__global__ void k5_P(const float* __restrict__ om,
                     const float* __restrict__ to_out_w,
                     unsigned short* __restrict__ Pbf) {
    __shared__ float Ast[64][68];   // [c][dl]  W_h tile
    __shared__ float Bs[64][68];    // [c][gl]  om_h tile
    int d0 = blockIdx.x * 64;
    int h  = blockIdx.y;
    int b  = blockIdx.z;
    int tid = threadIdx.x, tx = tid & 15, ty = tid >> 4;

    for (int i = tid; i < 1024; i += 256) {
        int dl = i >> 4, cq = i & 15;
        float4 v = *(const float4*)(to_out_w + (size_t)(d0 + dl)*DM_ + h*64 + cq*4);
        Ast[cq*4+0][dl] = v.x; Ast[cq*4+1][dl] = v.y;
        Ast[cq*4+2][dl] = v.z; Ast[cq*4+3][dl] = v.w;
    }
    for (int i = tid; i < 1024; i += 256) {
        int gl = i >> 4, cq = i & 15;
        float4 v = *(const float4*)(om + (size_t)(b*G_ + gl)*DM_ + h*64 + cq*4);
        Bs[cq*4+0][gl] = v.x; Bs[cq*4+1][gl] = v.y;
        Bs[cq*4+2][gl] = v.z; Bs[cq*4+3][gl] = v.w;
    }
    __syncthreads();

    float acc[4][4];
#pragma unroll
    for (int i = 0; i < 4; i++)
#pragma unroll
        for (int j = 0; j < 4; j++) acc[i][j] = 0.f;
#pragma unroll 8
    for (int k = 0; k < 64; k++) {
        float4 av = *(const float4*)&Ast[k][ty*4];   // d direction
        float4 bv = *(const float4*)&Bs[k][tx*4];    // g direction
        float aa[4] = {av.x, av.y, av.z, av.w};
        float bb[4] = {bv.x, bv.y, bv.z, bv.w};
#pragma unroll
        for (int i = 0; i < 4; i++)
#pragma unroll
            for (int j = 0; j < 4; j++) acc[i][j] += aa[i]*bb[j];
    }

#pragma unroll
    for (int i = 0; i < 4; i++) {
        int d = d0 + ty*4 + i;
        ushort4 o;
        o.x = f2bf(acc[i][0]); o.y = f2bf(acc[i][1]);
        o.z = f2bf(acc[i][2]); o.w = f2bf(acc[i][3]);
        *(ushort4*)(Pbf + ((size_t)(b*512) + d)*512 + h*64 + tx*4) = o;
    }
}

// ---------------------------------------------------------------------------
// k6: out0 = sw @ P + bias, bf16 MFMA. A staged from fp32 sw with in-register
// bf16 conversion (k0 eliminated); B (Pbf) via global_load_lds width-16.
// 128x128 tile, BK=64, 4 waves, proven round-3 schedule (2 barriers/tile).
// XOR chunk-swizzle on both LDS operands kills the 16-way ds_read conflict.
// Chunked bijective XCD remap (1600 = 8 x 200) for A-panel L2 reuse.
__global__ __launch_bounds__(256) void k6_fp(
        const float* __restrict__ sw,
        const unsigned short* __restrict__ Pbf,
        const float* __restrict__ bias,
        float* __restrict__ out0) {
    __shared__ unsigned short As[128*64];   // 16 KB, chunk-swizzled
    __shared__ unsigned short Bs[128*64];   // 16 KB, chunk-swizzled
    int wg  = blockIdx.x;
    int fid = (wg & 7)*200 + (wg >> 3);
    int dt  = fid & 3;
    int t2  = fid >> 2;            // 0..399
    int nt  = t2 % 25;
    int b   = t2 / 25;
    int d0 = dt * 128;
    int n0 = nt * 128;
    int tid = threadIdx.x;
    int lane = tid & 63, wid = tid >> 6;
    int wm = wid & 1, wn = wid >> 1;
    int quad = lane >> 4, m16 = lane & 15;
    int lrow = lane >> 3;
    int lsw  = ((lane & 7) ^ (lrow & 7)) * 8;

    f32x4 acc[4][4] = {};

    for (int kt = 0; kt < 8; kt++) {
        // A: fp32 global -> bf16 regs -> swizzled ds_write
        const float* Ab = sw + ((size_t)(b*8 + kt) * N_ + n0) * 64;
#pragma unroll
        for (int r = 0; r < 8; r++) {
            int f = r*256 + tid;
            int nl = f >> 4;
            float4 v = make_float4(0.f,0.f,0.f,0.f);
            if (n0 + nl < N_) v = ((const float4*)Ab)[f];
            ushort4 o;
            o.x = f2bf(v.x); o.y = f2bf(v.y); o.z = f2bf(v.z); o.w = f2bf(v.w);
            // logical 8-elem chunk ch of row stored at phys chunk ch^(row&7)
            int row = f >> 4, ch = (f & 15) >> 1, hf = f & 1;
            *(ushort4*)&As[row*64 + ((ch ^ (row & 7))*8 + hf*4)] = o;
        }
        // B: rows d (stride 512 elems), pre-swizzled global src, linear LDS dest
        const unsigned short* Bb = Pbf + ((size_t)(b*512) + d0)*512 + kt*64;
#pragma unroll
        for (int c = wid; c < 16; c += 4) {
            const unsigned short* gp = Bb + (size_t)(c*8 + lrow)*512 + lsw;
            __builtin_amdgcn_global_load_lds(
                (const __attribute__((address_space(1))) unsigned int*)gp,
                (__attribute__((address_space(3))) unsigned int*)&Bs[c*512],
                16, 0, 0);
        }
        __syncthreads();
#pragma unroll
        for (int ks = 0; ks < 2; ks++) {
            int csw = ((ks*4 + quad) ^ (m16 & 7)) * 8;
            short8 av[4], bv[4];
#pragma unroll
            for (int mt = 0; mt < 4; mt++)
                av[mt] = *(short8*)&As[(wm*64 + mt*16 + m16)*64 + csw];
#pragma unroll
            for (int nt2 = 0; nt2 < 4; nt2++)
                bv[nt2] = *(short8*)&Bs[(wn*64 + nt2*16 + m16)*64 + csw];
#pragma unroll
            for (int mt = 0; mt < 4; mt++)
#pragma unroll
                for (int nt2 = 0; nt2 < 4; nt2++)
                    acc[mt][nt2] = __builtin_amdgcn_mfma_f32_16x16x32_bf16(
                        av[mt], bv[nt2], acc[mt][nt2], 0, 0, 0);
        }
        __syncthreads();
    }
#pragma unroll
    for (int nt2 = 0; nt2 < 4; nt2++) {
        int dcol = d0 + wn*64 + nt2*16 + m16;
        float bval = bias[dcol];
#pragma unroll
        for (int mt = 0; mt < 4; mt++) {
#pragma unroll
            for (int r = 0; r < 4; r++) {
                int n = n0 + wm*64 + mt*16 + quad*4 + r;
                if (n < N_)
                    out0[((size_t)b*N_ + n)*DIM_ + dcol] = acc[mt][nt2][r] + bval;
            }
        }
    }
}

// ---------------------------------------------------------------------------
extern "C" void kernel_launch(void* const* d_in, const int* in_sizes, int n_in,
                              void* d_out, int out_size, void* d_ws, size_t ws_size,
                              hipStream_t stream) {
    const float* st      = (const float*)d_in[0];
    const float* sw      = (const float*)d_in[1];
    const float* w_in    = (const float*)d_in[2];
    const float* conv_w  = (const float*)d_in[3];
    const float* conv_b  = (const float*)d_in[4];
    const float* dt_bias = (const float*)d_in[5];
    const float* A_log   = (const float*)d_in[6];
    const float* Dvec    = (const float*)d_in[7];
    const float* fc_D_w  = (const float*)d_in[8];
    const float* norm_w  = (const float*)d_in[9];
    const float* w_out   = (const float*)d_in[10];
    const float* to_out_w= (const float*)d_in[11];
    const float* to_out_b= (const float*)d_in[12];
    float* out = (float*)d_out;
    float* ws  = (float*)d_ws;

    // layout (floats): [Pbf][temporaries]
    unsigned short* Pbf = (unsigned short*)ws;                 // 2,097,152 fl
    float* base = ws + 2097152;
    float* zx   = base;                                        // 1,067,008
    float* xb   = zx  + (size_t)B_*G_*DINPROJ_;                // 524,288
    float* tblf = xb  + (size_t)B_*G_*DM_;                     // 32,768
    float* Cv   = tblf+ (size_t)B_*G_*NH_*4;                   // 1,024
    float* dco  = Cv  + B_*G_;                                 // 8,192
    float* yfw  = dco + B_*G_*NH_;                             // 524,288
    float* ybw  = yfw + (size_t)B_*G_*DM_;                     // 524,288
    float* yn   = ybw + (size_t)B_*G_*DM_;                     // 524,288
    float* om   = yn  + (size_t)B_*G_*DM_;                     // 524,288

    dim3 g1(17, 16);
    k1_inproj<<<g1, 256, 0, stream>>>(st, w_in, zx);
    k2_conv  <<<B_*G_, 256, 0, stream>>>(zx, conv_w, conv_b, dt_bias, A_log,
                                         fc_D_w, Dvec, xb, Cv, tblf, dco);
    dim3 g3(B_*HEADS_, 2);
    k3_scan  <<<g3, 64, 0, stream>>>(xb, Cv, tblf, dco, yfw, ybw);
    k4a_rms  <<<B_*G_, 256, 0, stream>>>(yfw, ybw, zx, norm_w, yn);
    dim3 g4(8, 16);
    k4b_wout <<<g4, 256, 0, stream>>>(yn, w_out, om, out + OUT2_OFS);
    dim3 g5(8, 8, 16);
    k5_P     <<<g5, 256, 0, stream>>>(om, to_out_w, Pbf);
    k6_fp    <<<1600, 256, 0, stream>>>(sw, Pbf, to_out_b, out + OUT0_OFS);
    hipMemcpyAsync(out + OUT1_OFS, st, (size_t)B_*HEADS_*G_*DH_*sizeof(float),
                   hipMemcpyDeviceToDevice, stream);
}

// Round 10
// 413.615 us; speedup vs baseline: 1.2494x; 1.2494x over previous
//
#include <hip/hip_runtime.h>
#include <math.h>

#define B_ 16
#define HEADS_ 8
#define G_ 64          // == L
#define DH_ 64
#define N_ 3131
#define DM_ 512
#define NH_ 8
#define DINPROJ_ 1042
#define CONVDIM_ 514
#define DIM_ 512

#define OUT0_OFS 0
#define OUT1_OFS (B_*N_*DIM_)
#define OUT2_OFS (B_*N_*DIM_ + B_*HEADS_*G_*DH_)

#define SW_ELEMS (B_*HEADS_*N_*64)   // 25,649,152

typedef __attribute__((ext_vector_type(8))) short short8;
typedef __attribute__((ext_vector_type(4))) float f32x4;

__device__ __forceinline__ float siluf(float v){ return v / (1.f + expf(-v)); }
__device__ __forceinline__ float softplusf(float v){ return (v > 20.f) ? v : log1pf(expf(v)); }
__device__ __forceinline__ unsigned short f2bf(float f){
    unsigned int u = __float_as_uint(f);
    unsigned int r = (u + 0x7fffu + ((u >> 16) & 1u)) >> 16;
    return (unsigned short)r;
}

// ---------------------------------------------------------------------------
// k0: sw fp32 -> bf16 (contiguous). 8 elems/thread. BW-bound, conversion
// belongs here (round-6 lesson: in-staging cvt is latency-serialized).
__global__ void k0_cvt(const float* __restrict__ sw, unsigned short* __restrict__ swb) {
    int i = blockIdx.x * 256 + threadIdx.x;       // group of 8
    const float4* p = (const float4*)(sw + (size_t)i * 8);
    float4 v0 = p[0], v1 = p[1];
    short8 o;
    o[0]=f2bf(v0.x); o[1]=f2bf(v0.y); o[2]=f2bf(v0.z); o[3]=f2bf(v0.w);
    o[4]=f2bf(v1.x); o[5]=f2bf(v1.y); o[6]=f2bf(v1.z); o[7]=f2bf(v1.w);
    *(short8*)(swb + (size_t)i * 8) = o;
}

// ---------------------------------------------------------------------------
// k1: zx[bl][j] = sum_d u[bl][d] * w_in[j][d]
__global__ void k1_inproj(const float* __restrict__ st,
                          const float* __restrict__ w_in,
                          float* __restrict__ zx) {
    __shared__ float Ast[64][68];   // [c][l]
    __shared__ float Bs[64][68];    // [c][jl]
    int j0 = blockIdx.x * 64;
    int b  = blockIdx.y;
    int tid = threadIdx.x, tx = tid & 15, ty = tid >> 4;
    float acc[4][4];
#pragma unroll
    for (int i = 0; i < 4; i++)
#pragma unroll
        for (int j = 0; j < 4; j++) acc[i][j] = 0.f;

    for (int h = 0; h < 8; h++) {
        const float* Ab = st + ((size_t)(b*8 + h) * 64) * 64;
        for (int i = tid; i < 1024; i += 256) {
            int l = i >> 4, cq = i & 15;
            float4 v = *(const float4*)(Ab + l*64 + cq*4);
            Ast[cq*4+0][l] = v.x; Ast[cq*4+1][l] = v.y;
            Ast[cq*4+2][l] = v.z; Ast[cq*4+3][l] = v.w;
        }
        for (int i = tid; i < 1024; i += 256) {
            int jl = i >> 4, cq = i & 15;
            int j = j0 + jl;
            float4 v = make_float4(0.f,0.f,0.f,0.f);
            if (j < DINPROJ_) v = *(const float4*)(w_in + (size_t)j*DM_ + h*64 + cq*4);
            Bs[cq*4+0][jl] = v.x; Bs[cq*4+1][jl] = v.y;
            Bs[cq*4+2][jl] = v.z; Bs[cq*4+3][jl] = v.w;
        }
        __syncthreads();
#pragma unroll 8
        for (int k = 0; k < 64; k++) {
            float4 av = *(const float4*)&Ast[k][ty*4];
            float4 bv = *(const float4*)&Bs[k][tx*4];
            float aa[4] = {av.x, av.y, av.z, av.w};
            float bb[4] = {bv.x, bv.y, bv.z, bv.w};
#pragma unroll
            for (int i = 0; i < 4; i++)
#pragma unroll
                for (int j = 0; j < 4; j++) acc[i][j] += aa[i]*bb[j];
        }
        __syncthreads();
    }
#pragma unroll
    for (int i = 0; i < 4; i++) {
        int bl = b*64 + ty*4 + i;
#pragma unroll
        for (int j = 0; j < 4; j++) {
            int jj = j0 + tx*4 + j;
            if (jj < DINPROJ_) zx[(size_t)bl*DINPROJ_ + jj] = acc[i][j];
        }
    }
}

// ---------------------------------------------------------------------------
// k2: conv3+silu -> x,(B,C); scan tables a=exp(dt*A), bb=dt*Bv; dcoef
// (zs removed: k4a computes silu(z) inline from zx)
__global__ void k2_conv(const float* __restrict__ zx,
                        const float* __restrict__ conv_w,
                        const float* __restrict__ conv_b,
                        const float* __restrict__ dt_bias,
                        const float* __restrict__ A_log,
                        const float* __restrict__ fc_D_w,
                        const float* __restrict__ Dvec,
                        float* __restrict__ x,
                        float* __restrict__ Cv, float* __restrict__ tblf,
                        float* __restrict__ dco) {
    int bl = blockIdx.x; int b = bl >> 6, l = bl & 63;
    __shared__ float sx[DM_];
    __shared__ float sBv;
    const float* zrow = zx + (size_t)bl * DINPROJ_;

    for (int ch = threadIdx.x; ch < CONVDIM_; ch += 256) {
        float v = conv_b[ch];
#pragma unroll
        for (int k = 0; k < 3; k++) {
            int t = l - 2 + k;
            if (t >= 0) v += conv_w[ch*3 + k] * zx[(size_t)(b*G_ + t) * DINPROJ_ + DM_ + ch];
        }
        float sv = siluf(v);
        if (ch < DM_)      { x[(size_t)bl*DM_ + ch] = sv; sx[ch] = sv; }
        else if (ch == DM_){ sBv = sv; }
        else               { Cv[bl] = sv; }
    }
    __syncthreads();
    if (threadIdx.x < 16) {
        int i = threadIdx.x; int h = i & 7;
        float dt = softplusf(zrow[DM_ + CONVDIM_ + i] + dt_bias[h]);
        float Ah = -expf(A_log[h]);
        float a  = expf(dt * Ah);
        float bb = dt * sBv;
        float* t4 = tblf + ((size_t)bl*NH_ + h)*4;
        if (i < 8) { t4[0] = a; t4[1] = bb; }
        else       { t4[2] = a; t4[3] = bb; }
    }
    // dco: all 256 threads; 32 lanes per head, float4 loads, shuffle reduce
    {
        int h = threadIdx.x >> 5, l32 = threadIdx.x & 31;
        const float* fr = fc_D_w + (size_t)h * DM_;
        float s = 0.f;
#pragma unroll
        for (int q = 0; q < 4; q++) {
            int d = q*128 + l32*4;
            float4 w4 = *(const float4*)(fr + d);
            float4 x4 = *(const float4*)(&sx[d]);
            s += w4.x*x4.x + w4.y*x4.y + w4.z*x4.z + w4.w*x4.w;
        }
#pragma unroll
        for (int o = 16; o > 0; o >>= 1) s += __shfl_down(s, o, 32);
        if (l32 == 0) dco[bl*NH_ + h] = s + Dvec[h];
    }
}

// ---------------------------------------------------------------------------
// k3: directional scan. dir=0: yfw = dterm + y_fw ; dir=1: ybw = y_bw
// grid (B_*HEADS_, 2), 64 threads
__global__ void k3_scan(const float* __restrict__ x, const float* __restrict__ Cv,
                        const float* __restrict__ tblf, const float* __restrict__ dco,
                        float* __restrict__ yfw, float* __restrict__ ybw) {
    int bh = blockIdx.x; int b = bh >> 3, h = bh & 7;
    int dir = blockIdx.y;
    int c = threadIdx.x;
    __shared__ float sA[64], sB[64], sC[64], sD[64];
    {
        int bl = b*64 + c;
        const float* t4 = tblf + ((size_t)bl*NH_ + h)*4;
        sA[c] = dir ? t4[2] : t4[0];
        sB[c] = dir ? t4[3] : t4[1];
        sC[c] = Cv[bl];
        sD[c] = dco[bl*NH_ + h];
    }
    __syncthreads();
    const float* xr = x + (size_t)(b*64)*DM_ + h*64 + c;
    if (dir == 0) {
        float* yw = yfw + (size_t)(b*64)*DM_ + h*64 + c;
        float state = 0.f;
        float xv = xr[0];
#pragma unroll 4
        for (int t = 0; t < 64; t++) {
            float xn = (t < 63) ? xr[(t+1)*DM_] : 0.f;
            float val = xv * sD[t];
            if (t > 0) val += state * sC[t-1];
            yw[t*DM_] = val;
            state = sA[t]*state + sB[t]*xv;
            xv = xn;
        }
    } else {
        float* yw = ybw + (size_t)(b*64)*DM_ + h*64 + c;
        float state = 0.f;
        float xv = xr[63*DM_];
#pragma unroll 4
        for (int s = 63; s >= 0; s--) {
            float xn = (s > 0) ? xr[(s-1)*DM_] : 0.f;
            float val = (s < 63) ? state * sC[s+1] : 0.f;
            yw[s*DM_] = val;
            state = sA[s]*state + sB[s]*xv;
            xv = xn;
        }
    }
}

// ---------------------------------------------------------------------------
// k4a: y = (yfw+ybw)*silu(z from zx) ; RMSNorm -> yn
__global__ void k4a_rms(const float* __restrict__ yfw, const float* __restrict__ ybw,
                        const float* __restrict__ zx, const float* __restrict__ norm_w,
                        float* __restrict__ yn) {
    int bl = blockIdx.x;
    __shared__ float red[4];
    const float* zrow = zx + (size_t)bl * DINPROJ_;
    float vv[2]; float ss = 0.f;
#pragma unroll
    for (int r = 0; r < 2; r++) {
        int d = threadIdx.x + r*256;
        size_t i = (size_t)bl*DM_ + d;
        float v = (yfw[i] + ybw[i]) * siluf(zrow[d]);
        vv[r] = v; ss += v*v;
    }
#pragma unroll
    for (int o = 32; o > 0; o >>= 1) ss += __shfl_down(ss, o, 64);
    if ((threadIdx.x & 63) == 0) red[threadIdx.x >> 6] = ss;
    __syncthreads();
    float scale = rsqrtf((red[0]+red[1]+red[2]+red[3]) / (float)DM_ + 1e-5f);
#pragma unroll
    for (int r = 0; r < 2; r++) {
        int d = threadIdx.x + r*256;
        yn[(size_t)bl*DM_ + d] = vv[r] * scale * norm_w[d];
    }
}

// ---------------------------------------------------------------------------
// k4b: om[bl][j] = sum_d yn[bl][d]*w_out[j][d]; also out2
__global__ void k4b_wout(const float* __restrict__ yn,
                         const float* __restrict__ w_out,
                         float* __restrict__ om, float* __restrict__ out2) {
    __shared__ float Ast[64][68];
    __shared__ float Bs[64][68];
    int j0 = blockIdx.x * 64;
    int b  = blockIdx.y;
    int tid = threadIdx.x, tx = tid & 15, ty = tid >> 4;
    float acc[4][4];
#pragma unroll
    for (int i = 0; i < 4; i++)
#pragma unroll
        for (int j = 0; j < 4; j++) acc[i][j] = 0.f;

    for (int kt = 0; kt < 8; kt++) {
        const float* Ab = yn + (size_t)(b*64)*DM_ + kt*64;
        for (int i = tid; i < 1024; i += 256) {
            int l = i >> 4, cq = i & 15;
            float4 v = *(const float4*)(Ab + (size_t)l*DM_ + cq*4);
            Ast[cq*4+0][l] = v.x; Ast[cq*4+1][l] = v.y;
            Ast[cq*4+2][l] = v.z; Ast[cq*4+3][l] = v.w;
        }
        for (int i = tid; i < 1024; i += 256) {
            int jl = i >> 4, cq = i & 15;
            float4 v = *(const float4*)(w_out + (size_t)(j0 + jl)*DM_ + kt*64 + cq*4);
            Bs[cq*4+0][jl] = v.x; Bs[cq*4+1][jl] = v.y;
            Bs[cq*4+2][jl] = v.z; Bs[cq*4+3][jl] = v.w;
        }
        __syncthreads();
#pragma unroll 8
        for (int k = 0; k < 64; k++) {
            float4 av = *(const float4*)&Ast[k][ty*4];
            float4 bv = *(const float4*)&Bs[k][tx*4];
            float aa[4] = {av.x, av.y, av.z, av.w};
            float bb[4] = {bv.x, bv.y, bv.z, bv.w};
#pragma unroll
            for (int i = 0; i < 4; i++)
#pragma unroll
                for (int j = 0; j < 4; j++) acc[i][j] += aa[i]*bb[j];
        }
        __syncthreads();
    }
#pragma unroll
    for (int i = 0; i < 4; i++) {
        int l = ty*4 + i, bl = b*64 + l;
        float4 v = make_float4(acc[i][0], acc[i][1], acc[i][2], acc[i][3]);
        *(float4*)(om + (size_t)bl*DM_ + j0 + tx*4) = v;
        *(float4*)(out2 + (((size_t)(b*8 + blockIdx.x)*64 + l) << 6) + tx*4) = v;
    }
}

// ---------------------------------------------------------------------------
// k5: Pbf[b][d][h*64+g] = bf16( sum_c om[b,g,h*64+c] * to_out_w[d,h*64+c] )
// Block-diagonal per head: tiled fp32 outer-product GEMM, no spill.
__global__ void k5_P(const float* __restrict__ om,
                     const float* __restrict__ to_out_w,
                     unsigned short* __restrict__ Pbf) {
    __shared__ float Ast[64][68];   // [c][dl]  W_h tile
    __shared__ float Bs[64][68];    // [c][gl]  om_h tile
    int d0 = blockIdx.x * 64;
    int h  = blockIdx.y;
    int b  = blockIdx.z;
    int tid = threadIdx.x, tx = tid & 15, ty = tid >> 4;

    for (int i = tid; i < 1024; i += 256) {
        int dl = i >> 4, cq = i & 15;
        float4 v = *(const float4*)(to_out_w + (size_t)(d0 + dl)*DM_ + h*64 + cq*4);
        Ast[cq*4+0][dl] = v.x; Ast[cq*4+1][dl] = v.y;
        Ast[cq*4+2][dl] = v.z; Ast[cq*4+3][dl] = v.w;
    }
    for (int i = tid; i < 1024; i += 256) {
        int gl = i >> 4, cq = i & 15;
        float4 v = *(const float4*)(om + (size_t)(b*G_ + gl)*DM_ + h*64 + cq*4);
        Bs[cq*4+0][gl] = v.x; Bs[cq*4+1][gl] = v.y;
        Bs[cq*4+2][gl] = v.z; Bs[cq*4+3][gl] = v.w;
    }
    __syncthreads();

    float acc[4][4];
#pragma unroll
    for (int i = 0; i < 4; i++)
#pragma unroll
        for (int j = 0; j < 4; j++) acc[i][j] = 0.f;
#pragma unroll 8
    for (int k = 0; k < 64; k++) {
        float4 av = *(const float4*)&Ast[k][ty*4];   // d direction
        float4 bv = *(const float4*)&Bs[k][tx*4];    // g direction
        float aa[4] = {av.x, av.y, av.z, av.w};
        float bb[4] = {bv.x, bv.y, bv.z, bv.w};
#pragma unroll
        for (int i = 0; i < 4; i++)
#pragma unroll
            for (int j = 0; j < 4; j++) acc[i][j] += aa[i]*bb[j];
    }

#pragma unroll
    for (int i = 0; i < 4; i++) {
        int d = d0 + ty*4 + i;
        ushort4 o;
        o.x = f2bf(acc[i][0]); o.y = f2bf(acc[i][1]);
        o.z = f2bf(acc[i][2]); o.w = f2bf(acc[i][3]);
        *(ushort4*)(Pbf + ((size_t)(b*512) + d)*512 + h*64 + tx*4) = o;
    }
}

// ---------------------------------------------------------------------------
// k6 (async path): out0 = sw @ P + bias, bf16 MFMA, both operands via
// global_load_lds width-16. 256x128 tile, BK=64, 8 waves (512 thr).
// Bigger tile -> 2x compute per barrier-drain, more resident waves to
// overlap the vmcnt(0) stall (m114 mechanism); LDS 48 KB.
// XOR chunk-swizzle (both-sides) kills the 16-way ds_read conflict.
// Chunked bijective XCD remap (832 = 8 x 104); consecutive fid = the 4
// d-tiles of one A n-panel -> same XCD L2.
__global__ __launch_bounds__(512) void k6_bf(
        const unsigned short* __restrict__ swb,
        const unsigned short* __restrict__ Pbf,
        const float* __restrict__ bias,
        float* __restrict__ out0) {
    __shared__ unsigned short As[256*64];   // 32 KB, chunk-swizzled
    __shared__ unsigned short Bs[128*64];   // 16 KB, chunk-swizzled
    int wg  = blockIdx.x;
    int fid = (wg & 7)*104 + (wg >> 3);
    int dt  = fid & 3;
    int t2  = fid >> 2;            // 0..207
    int nt  = t2 % 13;
    int b   = t2 / 13;
    int d0 = dt * 128;
    int n0 = nt * 256;
    int tid = threadIdx.x;
    int lane = tid & 63, wid = tid >> 6;   // wid 0..7
    int wm = wid & 3, wn = wid >> 2;       // wm: n-subtile (4x64), wn: d-subtile (2x64)
    int quad = lane >> 4, m16 = lane & 15;
    int lrow = lane >> 3;
    int lsw  = ((lane & 7) ^ (lrow & 7)) * 8;

    f32x4 acc[4][4] = {};

    for (int kt = 0; kt < 8; kt++) {
        // A: 256 rows (clamped at N_-1 for the last tile), 32 chunks of 8 rows
        const unsigned short* Abase = swb + ((size_t)(b*8 + kt) * N_) * 64;
#pragma unroll
        for (int c = wid; c < 32; c += 8) {
            int rn = n0 + c*8 + lrow; if (rn > N_-1) rn = N_-1;
            __builtin_amdgcn_global_load_lds(
                (const __attribute__((address_space(1))) unsigned int*)(Abase + (size_t)rn*64 + lsw),
                (__attribute__((address_space(3))) unsigned int*)&As[c*512],
                16, 0, 0);
        }
        // B: rows d (stride 512 elems), 16 chunks
        const unsigned short* Bb = Pbf + ((size_t)(b*512) + d0)*512 + kt*64;
#pragma unroll
        for (int c = wid; c < 16; c += 8) {
            const unsigned short* gp = Bb + (size_t)(c*8 + lrow)*512 + lsw;
            __builtin_amdgcn_global_load_lds(
                (const __attribute__((address_space(1))) unsigned int*)gp,
                (__attribute__((address_space(3))) unsigned int*)&Bs[c*512],
                16, 0, 0);
        }
        __syncthreads();
#pragma unroll
        for (int ks = 0; ks < 2; ks++) {
            int csw = ((ks*4 + quad) ^ (m16 & 7)) * 8;
            short8 av[4], bv[4];
#pragma unroll
            for (int mt = 0; mt < 4; mt++)
                av[mt] = *(short8*)&As[(wm*64 + mt*16 + m16)*64 + csw];
#pragma unroll
            for (int nt2 = 0; nt2 < 4; nt2++)
                bv[nt2] = *(short8*)&Bs[(wn*64 + nt2*16 + m16)*64 + csw];
#pragma unroll
            for (int mt = 0; mt < 4; mt++)
#pragma unroll
                for (int nt2 = 0; nt2 < 4; nt2++)
                    acc[mt][nt2] = __builtin_amdgcn_mfma_f32_16x16x32_bf16(
                        av[mt], bv[nt2], acc[mt][nt2], 0, 0, 0);
        }
        __syncthreads();
    }
#pragma unroll
    for (int nt2 = 0; nt2 < 4; nt2++) {
        int dcol = d0 + wn*64 + nt2*16 + m16;
        float bval = bias[dcol];
#pragma unroll
        for (int mt = 0; mt < 4; mt++) {
#pragma unroll
            for (int r = 0; r < 4; r++) {
                int n = n0 + wm*64 + mt*16 + quad*4 + r;
                if (n < N_)
                    out0[((size_t)b*N_ + n)*DIM_ + dcol] = acc[mt][nt2][r] + bval;
            }
        }
    }
}

// ---------------------------------------------------------------------------
// k6 fallback (fp32 A staging, used only if ws too small for swb)
__global__ __launch_bounds__(256) void k6_fp(
        const float* __restrict__ sw,
        const unsigned short* __restrict__ Pbf,
        const float* __restrict__ bias,
        float* __restrict__ out0) {
    __shared__ unsigned short As[128*64];
    __shared__ unsigned short Bs[128*64];
    int wg  = blockIdx.x;
    int fid = (wg & 7)*200 + (wg >> 3);
    int dt  = fid & 3;
    int t2  = fid >> 2;
    int nt  = t2 % 25;
    int b   = t2 / 25;
    int d0 = dt * 128;
    int n0 = nt * 128;
    int tid = threadIdx.x;
    int lane = tid & 63, wid = tid >> 6;
    int wm = wid & 1, wn = wid >> 1;
    int quad = lane >> 4, m16 = lane & 15;
    int lrow = lane >> 3;
    int lsw  = ((lane & 7) ^ (lrow & 7)) * 8;

    f32x4 acc[4][4] = {};

    for (int kt = 0; kt < 8; kt++) {
        const float* Ab = sw + ((size_t)(b*8 + kt) * N_ + n0) * 64;
#pragma unroll
        for (int r = 0; r < 8; r++) {
            int f = r*256 + tid;
            int nl = f >> 4;
            float4 v = make_float4(0.f,0.f,0.f,0.f);
            if (n0 + nl < N_) v = ((const float4*)Ab)[f];
            ushort4 o;
            o.x = f2bf(v.x); o.y = f2bf(v.y); o.z = f2bf(v.z); o.w = f2bf(v.w);
            int row = f >> 4, ch = (f & 15) >> 1, hf = f & 1;
            *(ushort4*)&As[row*64 + ((ch ^ (row & 7))*8 + hf*4)] = o;
        }
        const unsigned short* Bb = Pbf + ((size_t)(b*512) + d0)*512 + kt*64;
#pragma unroll
        for (int c = wid; c < 16; c += 4) {
            const unsigned short* gp = Bb + (size_t)(c*8 + lrow)*512 + lsw;
            __builtin_amdgcn_global_load_lds(
                (const __attribute__((address_space(1))) unsigned int*)gp,
                (__attribute__((address_space(3))) unsigned int*)&Bs[c*512],
                16, 0, 0);
        }
        __syncthreads();
#pragma unroll
        for (int ks = 0; ks < 2; ks++) {
            int csw = ((ks*4 + quad) ^ (m16 & 7)) * 8;
            short8 av[4], bv[4];
#pragma unroll
            for (int mt = 0; mt < 4; mt++)
                av[mt] = *(short8*)&As[(wm*64 + mt*16 + m16)*64 + csw];
#pragma unroll
            for (int nt2 = 0; nt2 < 4; nt2++)
                bv[nt2] = *(short8*)&Bs[(wn*64 + nt2*16 + m16)*64 + csw];
#pragma unroll
            for (int mt = 0; mt < 4; mt++)
#pragma unroll
                for (int nt2 = 0; nt2 < 4; nt2++)
                    acc[mt][nt2] = __builtin_amdgcn_mfma_f32_16x16x32_bf16(
                        av[mt], bv[nt2], acc[mt][nt2], 0, 0, 0);
        }
        __syncthreads();
    }
#pragma unroll
    for (int nt2 = 0; nt2 < 4; nt2++) {
        int dcol = d0 + wn*64 + nt2*16 + m16;
        float bval = bias[dcol];
#pragma unroll
        for (int mt = 0; mt < 4; mt++) {
#pragma unroll
            for (int r = 0; r < 4; r++) {
                int n = n0 + wm*64 + mt*16 + quad*4 + r;
                if (n < N_)
                    out0[((size_t)b*N_ + n)*DIM_ + dcol] = acc[mt][nt2][r] + bval;
            }
        }
    }
}

// ---------------------------------------------------------------------------
extern "C" void kernel_launch(void* const* d_in, const int* in_sizes, int n_in,
                              void* d_out, int out_size, void* d_ws, size_t ws_size,
                              hipStream_t stream) {
    const float* st      = (const float*)d_in[0];
    const float* sw      = (const float*)d_in[1];
    const float* w_in    = (const float*)d_in[2];
    const float* conv_w  = (const float*)d_in[3];
    const float* conv_b  = (const float*)d_in[4];
    const float* dt_bias = (const float*)d_in[5];
    const float* A_log   = (const float*)d_in[6];
    const float* Dvec    = (const float*)d_in[7];
    const float* fc_D_w  = (const float*)d_in[8];
    const float* norm_w  = (const float*)d_in[9];
    const float* w_out   = (const float*)d_in[10];
    const float* to_out_w= (const float*)d_in[11];
    const float* to_out_b= (const float*)d_in[12];
    float* out = (float*)d_out;
    float* ws  = (float*)d_ws;

    // layout (floats): [Pbf][temporaries | swb (aliases temporaries, used after k5)]
    unsigned short* Pbf = (unsigned short*)ws;                 // 2,097,152 fl
    float* base = ws + 2097152;
    float* zx   = base;                                        // 1,067,008
    float* xb   = zx  + (size_t)B_*G_*DINPROJ_;                // 524,288
    float* tblf = xb  + (size_t)B_*G_*DM_;                     // 32,768
    float* Cv   = tblf+ (size_t)B_*G_*NH_*4;                   // 1,024
    float* dco  = Cv  + B_*G_;                                 // 8,192
    float* yfw  = dco + B_*G_*NH_;                             // 524,288
    float* ybw  = yfw + (size_t)B_*G_*DM_;                     // 524,288
    float* yn   = ybw + (size_t)B_*G_*DM_;                     // 524,288
    float* om   = yn  + (size_t)B_*G_*DM_;                     // 524,288
    // swb aliases [base ..): SW_ELEMS ushorts; k0 runs after k5 (zx consumed by k4a).
    unsigned short* swb = (unsigned short*)base;
    size_t need_async = (2097152 + (size_t)SW_ELEMS/2 + 64) * sizeof(float);
    bool async_ok = ws_size >= need_async;

    dim3 g1(17, 16);
    k1_inproj<<<g1, 256, 0, stream>>>(st, w_in, zx);
    k2_conv  <<<B_*G_, 256, 0, stream>>>(zx, conv_w, conv_b, dt_bias, A_log,
                                         fc_D_w, Dvec, xb, Cv, tblf, dco);
    dim3 g3(B_*HEADS_, 2);
    k3_scan  <<<g3, 64, 0, stream>>>(xb, Cv, tblf, dco, yfw, ybw);
    k4a_rms  <<<B_*G_, 256, 0, stream>>>(yfw, ybw, zx, norm_w, yn);
    dim3 g4(8, 16);
    k4b_wout <<<g4, 256, 0, stream>>>(yn, w_out, om, out + OUT2_OFS);
    dim3 g5(8, 8, 16);
    k5_P     <<<g5, 256, 0, stream>>>(om, to_out_w, Pbf);
    if (async_ok) {
        k0_cvt<<<SW_ELEMS/8/256, 256, 0, stream>>>(sw, swb);
        k6_bf <<<832, 512, 0, stream>>>(swb, Pbf, to_out_b, out + OUT0_OFS);
    } else {
        k6_fp <<<1600, 256, 0, stream>>>(sw, Pbf, to_out_b, out + OUT0_OFS);
    }
    hipMemcpyAsync(out + OUT1_OFS, st, (size_t)B_*HEADS_*G_*DH_*sizeof(float),
                   hipMemcpyDeviceToDevice, stream);
}

// Round 12
// 409.322 us; speedup vs baseline: 1.2625x; 1.0105x over previous
//
#include <hip/hip_runtime.h>
#include <math.h>

#define B_ 16
#define HEADS_ 8
#define G_ 64          // == L
#define DH_ 64
#define N_ 3131
#define DM_ 512
#define NH_ 8
#define DINPROJ_ 1042
#define CONVDIM_ 514
#define DIM_ 512

#define OUT0_OFS 0
#define OUT1_OFS (B_*N_*DIM_)
#define OUT2_OFS (B_*N_*DIM_ + B_*HEADS_*G_*DH_)

typedef __attribute__((ext_vector_type(8))) short short8;
typedef __attribute__((ext_vector_type(4))) float f32x4;

__device__ __forceinline__ float siluf(float v){ return v / (1.f + expf(-v)); }
__device__ __forceinline__ float softplusf(float v){ return (v > 20.f) ? v : log1pf(expf(v)); }
__device__ __forceinline__ unsigned short f2bf(float f){
    unsigned int u = __float_as_uint(f);
    unsigned int r = (u + 0x7fffu + ((u >> 16) & 1u)) >> 16;
    return (unsigned short)r;
}

// ---------------------------------------------------------------------------
// k1: zx[bl][j] = sum_d u[bl][d] * w_in[j][d]; j0==0 blocks also copy st->out1
__global__ void k1_inproj(const float* __restrict__ st,
                          const float* __restrict__ w_in,
                          float* __restrict__ zx,
                          float* __restrict__ out1) {
    __shared__ float Ast[64][68];   // [c][l]
    __shared__ float Bs[64][68];    // [c][jl]
    int j0 = blockIdx.x * 64;
    int b  = blockIdx.y;
    int tid = threadIdx.x, tx = tid & 15, ty = tid >> 4;
    float acc[4][4];
#pragma unroll
    for (int i = 0; i < 4; i++)
#pragma unroll
        for (int j = 0; j < 4; j++) acc[i][j] = 0.f;

    for (int h = 0; h < 8; h++) {
        const float* Ab = st + ((size_t)(b*8 + h) * 64) * 64;
        for (int i = tid; i < 1024; i += 256) {
            int l = i >> 4, cq = i & 15;
            float4 v = *(const float4*)(Ab + l*64 + cq*4);
            Ast[cq*4+0][l] = v.x; Ast[cq*4+1][l] = v.y;
            Ast[cq*4+2][l] = v.z; Ast[cq*4+3][l] = v.w;
            if (blockIdx.x == 0)
                *(float4*)(out1 + ((size_t)(b*8 + h) << 12) + l*64 + cq*4) = v;
        }
        for (int i = tid; i < 1024; i += 256) {
            int jl = i >> 4, cq = i & 15;
            int j = j0 + jl;
            float4 v = make_float4(0.f,0.f,0.f,0.f);
            if (j < DINPROJ_) v = *(const float4*)(w_in + (size_t)j*DM_ + h*64 + cq*4);
            Bs[cq*4+0][jl] = v.x; Bs[cq*4+1][jl] = v.y;
            Bs[cq*4+2][jl] = v.z; Bs[cq*4+3][jl] = v.w;
        }
        __syncthreads();
#pragma unroll 8
        for (int k = 0; k < 64; k++) {
            float4 av = *(const float4*)&Ast[k][ty*4];
            float4 bv = *(const float4*)&Bs[k][tx*4];
            float aa[4] = {av.x, av.y, av.z, av.w};
            float bb[4] = {bv.x, bv.y, bv.z, bv.w};
#pragma unroll
            for (int i = 0; i < 4; i++)
#pragma unroll
                for (int j = 0; j < 4; j++) acc[i][j] += aa[i]*bb[j];
        }
        __syncthreads();
    }
#pragma unroll
    for (int i = 0; i < 4; i++) {
        int bl = b*64 + ty*4 + i;
#pragma unroll
        for (int j = 0; j < 4; j++) {
            int jj = j0 + tx*4 + j;
            if (jj < DINPROJ_) zx[(size_t)bl*DINPROJ_ + jj] = acc[i][j];
        }
    }
}

// ---------------------------------------------------------------------------
// k2: conv3+silu -> x,(B,C); scan tables a=exp(dt*A), bb=dt*Bv; dcoef
__global__ void k2_conv(const float* __restrict__ zx,
                        const float* __restrict__ conv_w,
                        const float* __restrict__ conv_b,
                        const float* __restrict__ dt_bias,
                        const float* __restrict__ A_log,
                        const float* __restrict__ fc_D_w,
                        const float* __restrict__ Dvec,
                        float* __restrict__ x,
                        float* __restrict__ Cv, float* __restrict__ tblf,
                        float* __restrict__ dco) {
    int bl = blockIdx.x; int b = bl >> 6, l = bl & 63;
    __shared__ float sx[DM_];
    __shared__ float sBv;
    const float* zrow = zx + (size_t)bl * DINPROJ_;

    for (int ch = threadIdx.x; ch < CONVDIM_; ch += 256) {
        float v = conv_b[ch];
#pragma unroll
        for (int k = 0; k < 3; k++) {
            int t = l - 2 + k;
            if (t >= 0) v += conv_w[ch*3 + k] * zx[(size_t)(b*G_ + t) * DINPROJ_ + DM_ + ch];
        }
        float sv = siluf(v);
        if (ch < DM_)      { x[(size_t)bl*DM_ + ch] = sv; sx[ch] = sv; }
        else if (ch == DM_){ sBv = sv; }
        else               { Cv[bl] = sv; }
    }
    __syncthreads();
    if (threadIdx.x < 16) {
        int i = threadIdx.x; int h = i & 7;
        float dt = softplusf(zrow[DM_ + CONVDIM_ + i] + dt_bias[h]);
        float Ah = -expf(A_log[h]);
        float a  = expf(dt * Ah);
        float bb = dt * sBv;
        float* t4 = tblf + ((size_t)bl*NH_ + h)*4;
        if (i < 8) { t4[0] = a; t4[1] = bb; }
        else       { t4[2] = a; t4[3] = bb; }
    }
    // dco: all 256 threads; 32 lanes per head, float4 loads, shuffle reduce
    {
        int h = threadIdx.x >> 5, l32 = threadIdx.x & 31;
        const float* fr = fc_D_w + (size_t)h * DM_;
        float s = 0.f;
#pragma unroll
        for (int q = 0; q < 4; q++) {
            int d = q*128 + l32*4;
            float4 w4 = *(const float4*)(fr + d);
            float4 x4 = *(const float4*)(&sx[d]);
            s += w4.x*x4.x + w4.y*x4.y + w4.z*x4.z + w4.w*x4.w;
        }
#pragma unroll
        for (int o = 16; o > 0; o >>= 1) s += __shfl_down(s, o, 32);
        if (l32 == 0) dco[bl*NH_ + h] = s + Dvec[h];
    }
}

// ---------------------------------------------------------------------------
// k3: directional scan. dir=0: yfw = dterm + y_fw ; dir=1: ybw = y_bw
__global__ void k3_scan(const float* __restrict__ x, const float* __restrict__ Cv,
                        const float* __restrict__ tblf, const float* __restrict__ dco,
                        float* __restrict__ yfw, float* __restrict__ ybw) {
    int bh = blockIdx.x; int b = bh >> 3, h = bh & 7;
    int dir = blockIdx.y;
    int c = threadIdx.x;
    __shared__ float sA[64], sB[64], sC[64], sD[64];
    {
        int bl = b*64 + c;
        const float* t4 = tblf + ((size_t)bl*NH_ + h)*4;
        sA[c] = dir ? t4[2] : t4[0];
        sB[c] = dir ? t4[3] : t4[1];
        sC[c] = Cv[bl];
        sD[c] = dco[bl*NH_ + h];
    }
    __syncthreads();
    const float* xr = x + (size_t)(b*64)*DM_ + h*64 + c;
    if (dir == 0) {
        float* yw = yfw + (size_t)(b*64)*DM_ + h*64 + c;
        float state = 0.f;
        float xv = xr[0];
#pragma unroll 4
        for (int t = 0; t < 64; t++) {
            float xn = (t < 63) ? xr[(t+1)*DM_] : 0.f;
            float val = xv * sD[t];
            if (t > 0) val += state * sC[t-1];
            yw[t*DM_] = val;
            state = sA[t]*state + sB[t]*xv;
            xv = xn;
        }
    } else {
        float* yw = ybw + (size_t)(b*64)*DM_ + h*64 + c;
        float state = 0.f;
        float xv = xr[63*DM_];
#pragma unroll 4
        for (int s = 63; s >= 0; s--) {
            float xn = (s > 0) ? xr[(s-1)*DM_] : 0.f;
            float val = (s < 63) ? state * sC[s+1] : 0.f;
            yw[s*DM_] = val;
            state = sA[s]*state + sB[s]*xv;
            xv = xn;
        }
    }
}

// ---------------------------------------------------------------------------
// k4a: y = (yfw+ybw)*silu(z from zx) ; RMSNorm -> yn
__global__ void k4a_rms(const float* __restrict__ yfw, const float* __restrict__ ybw,
                        const float* __restrict__ zx, const float* __restrict__ norm_w,
                        float* __restrict__ yn) {
    int bl = blockIdx.x;
    __shared__ float red[4];
    const float* zrow = zx + (size_t)bl * DINPROJ_;
    float vv[2]; float ss = 0.f;
#pragma unroll
    for (int r = 0; r < 2; r++) {
        int d = threadIdx.x + r*256;
        size_t i = (size_t)bl*DM_ + d;
        float v = (yfw[i] + ybw[i]) * siluf(zrow[d]);
        vv[r] = v; ss += v*v;
    }
#pragma unroll
    for (int o = 32; o > 0; o >>= 1) ss += __shfl_down(ss, o, 64);
    if ((threadIdx.x & 63) == 0) red[threadIdx.x >> 6] = ss;
    __syncthreads();
    float scale = rsqrtf((red[0]+red[1]+red[2]+red[3]) / (float)DM_ + 1e-5f);
#pragma unroll
    for (int r = 0; r < 2; r++) {
        int d = threadIdx.x + r*256;
        yn[(size_t)bl*DM_ + d] = vv[r] * scale * norm_w[d];
    }
}

// ---------------------------------------------------------------------------
// k4b: om[bl][j] = sum_d yn[bl][d]*w_out[j][d]; also out2
__global__ void k4b_wout(const float* __restrict__ yn,
                         const float* __restrict__ w_out,
                         float* __restrict__ om, float* __restrict__ out2) {
    __shared__ float Ast[64][68];
    __shared__ float Bs[64][68];
    int j0 = blockIdx.x * 64;
    int b  = blockIdx.y;
    int tid = threadIdx.x, tx = tid & 15, ty = tid >> 4;
    float acc[4][4];
#pragma unroll
    for (int i = 0; i < 4; i++)
#pragma unroll
        for (int j = 0; j < 4; j++) acc[i][j] = 0.f;

    for (int kt = 0; kt < 8; kt++) {
        const float* Ab = yn + (size_t)(b*64)*DM_ + kt*64;
        for (int i = tid; i < 1024; i += 256) {
            int l = i >> 4, cq = i & 15;
            float4 v = *(const float4*)(Ab + (size_t)l*DM_ + cq*4);
            Ast[cq*4+0][l] = v.x; Ast[cq*4+1][l] = v.y;
            Ast[cq*4+2][l] = v.z; Ast[cq*4+3][l] = v.w;
        }
        for (int i = tid; i < 1024; i += 256) {
            int jl = i >> 4, cq = i & 15;
            float4 v = *(const float4*)(w_out + (size_t)(j0 + jl)*DM_ + kt*64 + cq*4);
            Bs[cq*4+0][jl] = v.x; Bs[cq*4+1][jl] = v.y;
            Bs[cq*4+2][jl] = v.z; Bs[cq*4+3][jl] = v.w;
        }
        __syncthreads();
#pragma unroll 8
        for (int k = 0; k < 64; k++) {
            float4 av = *(const float4*)&Ast[k][ty*4];
            float4 bv = *(const float4*)&Bs[k][tx*4];
            float aa[4] = {av.x, av.y, av.z, av.w};
            float bb[4] = {bv.x, bv.y, bv.z, bv.w};
#pragma unroll
            for (int i = 0; i < 4; i++)
#pragma unroll
                for (int j = 0; j < 4; j++) acc[i][j] += aa[i]*bb[j];
        }
        __syncthreads();
    }
#pragma unroll
    for (int i = 0; i < 4; i++) {
        int l = ty*4 + i, bl = b*64 + l;
        float4 v = make_float4(acc[i][0], acc[i][1], acc[i][2], acc[i][3]);
        *(float4*)(om + (size_t)bl*DM_ + j0 + tx*4) = v;
        *(float4*)(out2 + (((size_t)(b*8 + blockIdx.x)*64 + l) << 6) + tx*4) = v;
    }
}

// ---------------------------------------------------------------------------
// k5: Pbf[b][d][h*64+g] = bf16( sum_c om[b,g,h*64+c] * to_out_w[d,h*64+c] )
__global__ void k5_P(const float* __restrict__ om,
                     const float* __restrict__ to_out_w,
                     unsigned short* __restrict__ Pbf) {
    __shared__ float Ast[64][68];   // [c][dl]  W_h tile
    __shared__ float Bs[64][68];    // [c][gl]  om_h tile
    int d0 = blockIdx.x * 64;
    int h  = blockIdx.y;
    int b  = blockIdx.z;
    int tid = threadIdx.x, tx = tid & 15, ty = tid >> 4;

    for (int i = tid; i < 1024; i += 256) {
        int dl = i >> 4, cq = i & 15;
        float4 v = *(const float4*)(to_out_w + (size_t)(d0 + dl)*DM_ + h*64 + cq*4);
        Ast[cq*4+0][dl] = v.x; Ast[cq*4+1][dl] = v.y;
        Ast[cq*4+2][dl] = v.z; Ast[cq*4+3][dl] = v.w;
    }
    for (int i = tid; i < 1024; i += 256) {
        int gl = i >> 4, cq = i & 15;
        float4 v = *(const float4*)(om + (size_t)(b*G_ + gl)*DM_ + h*64 + cq*4);
        Bs[cq*4+0][gl] = v.x; Bs[cq*4+1][gl] = v.y;
        Bs[cq*4+2][gl] = v.z; Bs[cq*4+3][gl] = v.w;
    }
    __syncthreads();

    float acc[4][4];
#pragma unroll
    for (int i = 0; i < 4; i++)
#pragma unroll
        for (int j = 0; j < 4; j++) acc[i][j] = 0.f;
#pragma unroll 8
    for (int k = 0; k < 64; k++) {
        float4 av = *(const float4*)&Ast[k][ty*4];   // d direction
        float4 bv = *(const float4*)&Bs[k][tx*4];    // g direction
        float aa[4] = {av.x, av.y, av.z, av.w};
        float bb[4] = {bv.x, bv.y, bv.z, bv.w};
#pragma unroll
        for (int i = 0; i < 4; i++)
#pragma unroll
            for (int j = 0; j < 4; j++) acc[i][j] += aa[i]*bb[j];
    }

#pragma unroll
    for (int i = 0; i < 4; i++) {
        int d = d0 + ty*4 + i;
        ushort4 o;
        o.x = f2bf(acc[i][0]); o.y = f2bf(acc[i][1]);
        o.z = f2bf(acc[i][2]); o.w = f2bf(acc[i][3]);
        *(ushort4*)(Pbf + ((size_t)(b*512) + d)*512 + h*64 + tx*4) = o;
    }
}

// ---------------------------------------------------------------------------
// k6: out0 = sw @ P + bias. A read DIRECTLY as fp32 via global_load_lds
// (async DMA — no reg-staging latency), converted to bf16 after ds_read with
// v_cvt_pk_bf16_f32 (RNE == f2bf). Eliminates k0 and the swb round-trip.
// fp32 A swizzle: 16B slot s at row r holds logical slot s^(r&15); a fragment
// (8 floats) stays 32B-contiguous at chunk lc^((r>>1)&7) with its two 16B
// halves swapped when r odd -> per-b128 bank occupancy = the 8/bank floor.
// B path (bf16 Pbf) verbatim from the verified round-3 kernel.
// 128x128 tile, BK=64, 4 waves, LDS 48 KB; bijective 8x200 XCD remap.
__global__ __launch_bounds__(256) void k6_direct(
        const float* __restrict__ sw,
        const unsigned short* __restrict__ Pbf,
        const float* __restrict__ bias,
        float* __restrict__ out0) {
    __shared__ float Asf[128*64];           // 32 KB, slot-swizzled fp32
    __shared__ unsigned short Bs[128*64];   // 16 KB, chunk-swizzled bf16
    int wg  = blockIdx.x;
    int fid = (wg & 7)*200 + (wg >> 3);
    int dt  = fid & 3;
    int t2  = fid >> 2;            // 0..399
    int nt  = t2 % 25;
    int b   = t2 / 25;
    int d0 = dt * 128;
    int n0 = nt * 128;
    int tid = threadIdx.x;
    int lane = tid & 63, wid = tid >> 6;
    int wm = wid & 1, wn = wid >> 1;
    int quad = lane >> 4, m16 = lane & 15;
    int lrow = lane >> 3;
    int lsw  = ((lane & 7) ^ (lrow & 7)) * 8;   // B staging src swizzle (bf16 elems)
    int l4   = lane >> 4;                        // A staging: row-within-4
    int pslt = lane & 15;                        // A staging: phys 16B slot
    int olo  = (m16 & 1) * 4;                    // A read: logical-lo half offset (floats)
    int ohi  = 4 - olo;
    int q2   = m16 >> 1;                         // == (r>>1)&7 for all fragment rows

    f32x4 acc[4][4] = {};

    for (int kt = 0; kt < 8; kt++) {
        // A: fp32, 32 wave-loads of 1 KB (4 rows each); src pre-swizzled,
        // rows clamped to N_-1 (direct input has no pad slack; masked at store)
        const float* Abase = sw + (size_t)(b*8 + kt) * N_ * 64;
#pragma unroll
        for (int c = wid; c < 32; c += 4) {
            int rl = c*4 + l4;                       // local row 0..127
            int rn = n0 + rl; if (rn > N_-1) rn = N_-1;
            int s  = pslt ^ ((c & 3)*4 + l4);        // logical 16B slot
            __builtin_amdgcn_global_load_lds(
                (const __attribute__((address_space(1))) unsigned int*)(Abase + (size_t)rn*64 + s*4),
                (__attribute__((address_space(3))) unsigned int*)&Asf[c*256],
                16, 0, 0);
        }
        // B: bf16 rows d (stride 512 elems), pre-swizzled src, linear dest
        const unsigned short* Bb = Pbf + ((size_t)(b*512) + d0)*512 + kt*64;
#pragma unroll
        for (int c = wid; c < 16; c += 4) {
            const unsigned short* gp = Bb + (size_t)(c*8 + lrow)*512 + lsw;
            __builtin_amdgcn_global_load_lds(
                (const __attribute__((address_space(1))) unsigned int*)gp,
                (__attribute__((address_space(3))) unsigned int*)&Bs[c*512],
                16, 0, 0);
        }
        __syncthreads();
#pragma unroll
        for (int ks = 0; ks < 2; ks++) {
            int lc   = ks*4 + quad;
            int achf = (lc ^ q2) * 8;                    // A phys chunk base (floats)
            int csw  = (lc ^ (m16 & 7)) * 8;             // B phys chunk base (bf16)
            short8 av[4], bv[4];
#pragma unroll
            for (int mt = 0; mt < 4; mt++) {
                const float* fb = &Asf[(wm*64 + mt*16 + m16)*64 + achf];
                f32x4 lo = *(const f32x4*)(fb + olo);    // logical floats k..k+3
                f32x4 hi = *(const f32x4*)(fb + ohi);    // logical floats k+4..k+7
                union { unsigned int u[4]; short8 s; } pk;
                asm("v_cvt_pk_bf16_f32 %0, %1, %2" : "=v"(pk.u[0]) : "v"(lo[0]), "v"(lo[1]));
                asm("v_cvt_pk_bf16_f32 %0, %1, %2" : "=v"(pk.u[1]) : "v"(lo[2]), "v"(lo[3]));
                asm("v_cvt_pk_bf16_f32 %0, %1, %2" : "=v"(pk.u[2]) : "v"(hi[0]), "v"(hi[1]));
                asm("v_cvt_pk_bf16_f32 %0, %1, %2" : "=v"(pk.u[3]) : "v"(hi[2]), "v"(hi[3]));
                av[mt] = pk.s;
            }
#pragma unroll
            for (int nt2 = 0; nt2 < 4; nt2++)
                bv[nt2] = *(short8*)&Bs[(wn*64 + nt2*16 + m16)*64 + csw];
#pragma unroll
            for (int mt = 0; mt < 4; mt++)
#pragma unroll
                for (int nt2 = 0; nt2 < 4; nt2++)
                    acc[mt][nt2] = __builtin_amdgcn_mfma_f32_16x16x32_bf16(
                        av[mt], bv[nt2], acc[mt][nt2], 0, 0, 0);
        }
        __syncthreads();
    }
#pragma unroll
    for (int nt2 = 0; nt2 < 4; nt2++) {
        int dcol = d0 + wn*64 + nt2*16 + m16;
        float bval = bias[dcol];
#pragma unroll
        for (int mt = 0; mt < 4; mt++) {
#pragma unroll
            for (int r = 0; r < 4; r++) {
                int n = n0 + wm*64 + mt*16 + quad*4 + r;
                if (n < N_)
                    out0[((size_t)b*N_ + n)*DIM_ + dcol] = acc[mt][nt2][r] + bval;
            }
        }
    }
}

// ---------------------------------------------------------------------------
extern "C" void kernel_launch(void* const* d_in, const int* in_sizes, int n_in,
                              void* d_out, int out_size, void* d_ws, size_t ws_size,
                              hipStream_t stream) {
    const float* st      = (const float*)d_in[0];
    const float* sw      = (const float*)d_in[1];
    const float* w_in    = (const float*)d_in[2];
    const float* conv_w  = (const float*)d_in[3];
    const float* conv_b  = (const float*)d_in[4];
    const float* dt_bias = (const float*)d_in[5];
    const float* A_log   = (const float*)d_in[6];
    const float* Dvec    = (const float*)d_in[7];
    const float* fc_D_w  = (const float*)d_in[8];
    const float* norm_w  = (const float*)d_in[9];
    const float* w_out   = (const float*)d_in[10];
    const float* to_out_w= (const float*)d_in[11];
    const float* to_out_b= (const float*)d_in[12];
    float* out = (float*)d_out;
    float* ws  = (float*)d_ws;

    // layout (floats): [Pbf][temporaries]  (~21 MB total)
    unsigned short* Pbf = (unsigned short*)ws;                 // 2,097,152 fl
    float* base = ws + 2097152;
    float* zx   = base;                                        // 1,067,008
    float* xb   = zx  + (size_t)B_*G_*DINPROJ_;                // 524,288
    float* tblf = xb  + (size_t)B_*G_*DM_;                     // 32,768
    float* Cv   = tblf+ (size_t)B_*G_*NH_*4;                   // 1,024
    float* dco  = Cv  + B_*G_;                                 // 8,192
    float* yfw  = dco + B_*G_*NH_;                             // 524,288
    float* ybw  = yfw + (size_t)B_*G_*DM_;                     // 524,288
    float* yn   = ybw + (size_t)B_*G_*DM_;                     // 524,288
    float* om   = yn  + (size_t)B_*G_*DM_;                     // 524,288

    dim3 g1(17, 16);
    k1_inproj<<<g1, 256, 0, stream>>>(st, w_in, zx, out + OUT1_OFS);
    k2_conv  <<<B_*G_, 256, 0, stream>>>(zx, conv_w, conv_b, dt_bias, A_log,
                                         fc_D_w, Dvec, xb, Cv, tblf, dco);
    dim3 g3(B_*HEADS_, 2);
    k3_scan  <<<g3, 64, 0, stream>>>(xb, Cv, tblf, dco, yfw, ybw);
    k4a_rms  <<<B_*G_, 256, 0, stream>>>(yfw, ybw, zx, norm_w, yn);
    dim3 g4(8, 16);
    k4b_wout <<<g4, 256, 0, stream>>>(yn, w_out, om, out + OUT2_OFS);
    dim3 g5(8, 8, 16);
    k5_P     <<<g5, 256, 0, stream>>>(om, to_out_w, Pbf);
    k6_direct<<<1600, 256, 0, stream>>>(sw, Pbf, to_out_b, out + OUT0_OFS);
}